// Round 1
// baseline (94.632 us; speedup 1.0000x reference)
//
#include <hip/hip_runtime.h>
#include <hip/hip_bf16.h>

// Conv2d: B=16, CIN=128, COUT=256, H=W=56, 3x3, stride1, pad1, fp32, + bias.
// Strategy: implicit GEMM in bf16 MFMA.
//   M = COUT(256), N = B*H*Wpad(16*56*64=57344), K = 9*CIN(1152)
// Pre-passes build (in d_ws):
//   x_t  : bf16 NHWC padded  [16][58][64][128]  (pad=1 baked in, W padded to 64)
//   w_t2 : bf16, per-K-step [36][co(256)][kg(4) swizzled][8ci]  (16KB per step)
// GEMM: 128x128 tile, BK=32, double-buffered LDS, global_load_lds(16B).

#define XT_BYTES   15204352u   // 16*58*64*128*2
#define SLACK      8192u
#define WT_OFFSET  (XT_BYTES + SLACK)          // 15212544
#define WT_BYTES   589824u                     // 36*256*32*2
#define WS_NEED    (WT_OFFSET + WT_BYTES)

typedef __bf16 bf16x8 __attribute__((ext_vector_type(8)));
typedef float  f32x4  __attribute__((ext_vector_type(4)));
typedef unsigned short ushort8v __attribute__((ext_vector_type(8)));

__device__ __forceinline__ unsigned short f2bf(float f) {
  unsigned u = __builtin_bit_cast(unsigned, f);
  u += 0x7fffu + ((u >> 16) & 1u);
  return (unsigned short)(u >> 16);
}

__device__ __forceinline__ void gll16(const void* g, void* l) {
  __builtin_amdgcn_global_load_lds(
      (const __attribute__((address_space(1))) unsigned int*)g,
      (__attribute__((address_space(3))) unsigned int*)l, 16, 0, 0);
}

// ---------------- pre-pass kernels ----------------

__global__ void fill_zero(uint4* p, int n16) {
  int i = blockIdx.x * blockDim.x + threadIdx.x;
  int stride = gridDim.x * blockDim.x;
  uint4 z; z.x = z.y = z.z = z.w = 0u;
  for (; i < n16; i += stride) p[i] = z;
}

// x[16][128][56][56] f32  ->  x_t[16][58][64][128] bf16 (interior only)
__global__ void xtrans(const float* __restrict__ x, unsigned short* __restrict__ xt) {
  __shared__ unsigned short tile[128][58];
  int blk = blockIdx.x;            // 896 = 16*56
  int b = blk / 56, h = blk % 56;
  int t = threadIdx.x;             // 256
  int ci = t >> 1, half = t & 1;
  const float* src = x + ((size_t)(b * 128 + ci)) * 3136 + h * 56 + half * 28;
  #pragma unroll
  for (int q = 0; q < 7; ++q) {
    float4 v = *(const float4*)&src[q * 4];
    int wb = half * 28 + q * 4;
    tile[ci][wb + 0] = f2bf(v.x);
    tile[ci][wb + 1] = f2bf(v.y);
    tile[ci][wb + 2] = f2bf(v.z);
    tile[ci][wb + 3] = f2bf(v.w);
  }
  __syncthreads();
  if (t < 224) {
    int wo = t >> 2, chunk = t & 3;
    unsigned short* dst = xt + (size_t)b * 475136 + (size_t)(h + 1) * 8192 +
                          (size_t)(wo + 1) * 128 + chunk * 32;
    #pragma unroll
    for (int q = 0; q < 4; ++q) {
      ushort8v v;
      #pragma unroll
      for (int j = 0; j < 8; ++j) v[j] = tile[chunk * 32 + q * 8 + j][wo];
      *(ushort8v*)&dst[q * 8] = v;
    }
  }
}

// w[256][128][3][3] f32 -> w_t2[36][256][4 swizzled][8] bf16
__global__ void wtrans(const float* __restrict__ wsrc, unsigned short* __restrict__ wt) {
  int ks = blockIdx.x;    // 36
  int co = threadIdx.x;   // 256
  int tap = ks >> 2, ci0 = (ks & 3) * 32;
  int kh = tap >= 6 ? 2 : (tap >= 3 ? 1 : 0);
  int kw = tap - kh * 3;
  const float* src = wsrc + (size_t)co * 1152 + ci0 * 9 + kh * 3 + kw;
  #pragma unroll
  for (int kg = 0; kg < 4; ++kg) {
    ushort8v v;
    #pragma unroll
    for (int j = 0; j < 8; ++j) v[j] = f2bf(src[(kg * 8 + j) * 9]);
    int slot = kg ^ ((co >> 1) & 3);
    *(ushort8v*)&wt[(size_t)ks * 8192 + co * 32 + slot * 8] = v;
  }
}

// ---------------- main GEMM kernel ----------------

__global__ __launch_bounds__(256) void conv_gemm(
    const unsigned short* __restrict__ xt,
    const unsigned short* __restrict__ wt,
    const float* __restrict__ bias,
    float* __restrict__ out) {
  __shared__ unsigned short ldsA[2][4096];   // [buf][128co x 32k] swizzled, 8KB each
  __shared__ unsigned short ldsB[2][4096];   // [buf][128px x 32k] swizzled

  int bid = blockIdx.x;
  int sw = (bid & 7) * 112 + (bid >> 3);     // XCD swizzle, 896 = 8*112
  int pm = sw & 1;
  int pn = sw >> 1;                          // 0..447
  int bimg = pn / 28;
  int h0 = (pn - bimg * 28) * 2;
  int co0 = pm * 128;

  int tid = threadIdx.x;
  int wv = tid >> 6, l = tid & 63;
  int wm = wv >> 1, wn = wv & 1;

  // A staging source (per-lane, bytes); per step add ks*16384
  const char* aS = (const char*)wt + co0 * 64 + wv * 2048 + l * 16;

  // B staging sources (two 1KB insts per wave); per step add soff
  const char* bS0;
  const char* bS1;
  {
    int slot = l & 3;
    int px0 = wv * 32 + (l >> 2);
    int kg0 = slot ^ ((px0 >> 1) & 3);
    bS0 = (const char*)xt + (size_t)bimg * 950272 +
          (size_t)(h0 + (px0 >> 6)) * 16384 + (px0 & 63) * 256 + kg0 * 16;
    int px1 = px0 + 16;
    int kg1 = slot ^ ((px1 >> 1) & 3);
    bS1 = (const char*)xt + (size_t)bimg * 950272 +
          (size_t)(h0 + (px1 >> 6)) * 16384 + (px1 & 63) * 256 + kg1 * 16;
  }

  // fragment read offsets (ushort units)
  int lm = l & 15, kgf = l >> 4;
  int co_b = wm * 64 + lm;
  int aoff = co_b * 32 + ((kgf ^ ((co_b >> 1) & 3)) * 8);
  int px_b = wn * 64 + lm;
  int boff = px_b * 32 + ((kgf ^ ((px_b >> 1) & 3)) * 8);

  f32x4 acc[4][4];
  #pragma unroll
  for (int m = 0; m < 4; ++m)
    #pragma unroll
    for (int n = 0; n < 4; ++n)
      acc[m][n] = (f32x4){0.f, 0.f, 0.f, 0.f};

  auto stage = [&](int ks, int buf) {
    int tap = ks >> 2;
    int kh = tap >= 6 ? 2 : (tap >= 3 ? 1 : 0);
    int kw = tap - kh * 3;
    int soff = kh * 16384 + kw * 256 + (ks & 3) * 64;
    const char* a = aS + ks * 16384;
    gll16(a,            (void*)&ldsA[buf][wv * 1024]);
    gll16(a + 1024,     (void*)&ldsA[buf][wv * 1024 + 512]);
    gll16(bS0 + soff,   (void*)&ldsB[buf][wv * 1024]);
    gll16(bS1 + soff,   (void*)&ldsB[buf][wv * 1024 + 512]);
  };

  stage(0, 0);
  __syncthreads();
  int buf = 0;
  for (int ks = 0; ks < 36; ++ks) {
    if (ks + 1 < 36) stage(ks + 1, buf ^ 1);
    bf16x8 av[4], bv[4];
    #pragma unroll
    for (int m = 0; m < 4; ++m)
      av[m] = *(const bf16x8*)&ldsA[buf][aoff + m * 512];
    #pragma unroll
    for (int n = 0; n < 4; ++n)
      bv[n] = *(const bf16x8*)&ldsB[buf][boff + n * 512];
    #pragma unroll
    for (int m = 0; m < 4; ++m)
      #pragma unroll
      for (int n = 0; n < 4; ++n)
        acc[m][n] = __builtin_amdgcn_mfma_f32_16x16x32_bf16(av[m], bv[n], acc[m][n], 0, 0, 0);
    __syncthreads();
    buf ^= 1;
  }

  // epilogue: bias + masked store (w' < 56)
  int hout = h0 + wn;
  int rq = l >> 4;
  #pragma unroll
  for (int m = 0; m < 4; ++m) {
    int co = co0 + wm * 64 + m * 16 + rq * 4;
    f32x4 bb = *(const f32x4*)&bias[co];
    size_t obase = ((size_t)bimg * 256 + co) * 3136 + (size_t)hout * 56;
    #pragma unroll
    for (int n = 0; n < 4; ++n) {
      int wp_ = n * 16 + lm;
      if (wp_ < 56) {
        float* o = out + obase + wp_;
        #pragma unroll
        for (int r = 0; r < 4; ++r)
          o[(size_t)r * 3136] = acc[m][n][r] + bb[r];
      }
    }
  }
}

// ---------------- fallback (tiny ws) ----------------

__global__ void conv_naive(const float* __restrict__ x, const float* __restrict__ w,
                           const float* __restrict__ bias, float* __restrict__ out) {
  int idx = blockIdx.x * 256 + threadIdx.x;
  if (idx >= 16 * 256 * 56 * 56) return;
  int wo = idx % 56; int t = idx / 56;
  int ho = t % 56; t /= 56;
  int co = t % 256; int b = t / 256;
  float acc = bias[co];
  for (int ci = 0; ci < 128; ++ci) {
    const float* xp = x + ((size_t)(b * 128 + ci)) * 3136;
    const float* wp = w + ((size_t)(co * 128 + ci)) * 9;
    for (int kh = 0; kh < 3; ++kh) {
      int hi = ho + kh - 1;
      if (hi < 0 || hi >= 56) continue;
      for (int kw = 0; kw < 3; ++kw) {
        int wi = wo + kw - 1;
        if (wi < 0 || wi >= 56) continue;
        acc += xp[hi * 56 + wi] * wp[kh * 3 + kw];
      }
    }
  }
  out[idx] = acc;
}

extern "C" void kernel_launch(void* const* d_in, const int* in_sizes, int n_in,
                              void* d_out, int out_size, void* d_ws, size_t ws_size,
                              hipStream_t stream) {
  const float* x    = (const float*)d_in[0];
  const float* wgt  = (const float*)d_in[1];
  const float* bias = (const float*)d_in[2];
  float* out = (float*)d_out;

  if (ws_size < (size_t)WS_NEED) {
    conv_naive<<<(16 * 256 * 56 * 56 + 255) / 256, 256, 0, stream>>>(x, wgt, bias, out);
    return;
  }

  unsigned short* xt = (unsigned short*)d_ws;
  unsigned short* wt = (unsigned short*)((char*)d_ws + WT_OFFSET);

  fill_zero<<<1024, 256, 0, stream>>>((uint4*)d_ws, (int)(WT_OFFSET / 16));
  xtrans<<<896, 256, 0, stream>>>(x, xt);
  wtrans<<<36, 256, 0, stream>>>(wgt, wt);
  conv_gemm<<<896, 256, 0, stream>>>(xt, wt, bias, out);
}

// Round 2
// 76.428 us; speedup vs baseline: 1.2382x; 1.2382x over previous
//
#include <hip/hip_runtime.h>
#include <hip/hip_bf16.h>

// Conv2d: B=16, CIN=128, COUT=256, H=W=56, 3x3, stride1, pad1, fp32, + bias.
// Implicit GEMM, bf16 MFMA. M=256(co), N=16*56*64=57344(px, W padded to 64), K=1152.
// R2: 256x256x32 tile, 8 waves, 3-deep LDS ring (96KB), 2 phases/K-tile,
// counted vmcnt(4) (T3+T4), setprio (T5), conflict-free pair-XOR LDS swizzle (T2),
// XCD swizzle (T1, 224=8*28). A pre-packed in staged-linear pre-swizzled order.

#define XT_BYTES   15204352u   // 16*58*64*128*2
#define SLACK      8192u
#define WT_OFFSET  (XT_BYTES + SLACK)
#define WT_BYTES   589824u     // 36 * 16384
#define WS_NEED    (WT_OFFSET + WT_BYTES)

typedef __bf16 bf16x8 __attribute__((ext_vector_type(8)));
typedef float  f32x4  __attribute__((ext_vector_type(4)));
typedef unsigned short ushort8v __attribute__((ext_vector_type(8)));

__device__ __forceinline__ unsigned short f2bf(float f) {
  unsigned u = __builtin_bit_cast(unsigned, f);
  u += 0x7fffu + ((u >> 16) & 1u);
  return (unsigned short)(u >> 16);
}

__device__ __forceinline__ void gll16(const void* g, const void* l) {
  __builtin_amdgcn_global_load_lds(
      (const __attribute__((address_space(1))) unsigned int*)g,
      (__attribute__((address_space(3))) unsigned int*)l, 16, 0, 0);
}

// ---------------- pre-pass kernels ----------------

__global__ void fill_zero(uint4* p, int n16) {
  int i = blockIdx.x * blockDim.x + threadIdx.x;
  int stride = gridDim.x * blockDim.x;
  uint4 z; z.x = z.y = z.z = z.w = 0u;
  for (; i < n16; i += stride) p[i] = z;
}

// x[16][128][56][56] f32 -> x_t[16][58][64][128] bf16 (interior at [1..56][1..56])
__global__ void xtrans(const float* __restrict__ x, unsigned short* __restrict__ xt) {
  __shared__ unsigned short tile[128][58];
  int blk = blockIdx.x;            // 896 = 16*56
  int b = blk / 56, h = blk % 56;
  int t = threadIdx.x;             // 256
  int ci = t >> 1, half = t & 1;
  const float* src = x + ((size_t)(b * 128 + ci)) * 3136 + h * 56 + half * 28;
  #pragma unroll
  for (int q = 0; q < 7; ++q) {
    float4 v = *(const float4*)&src[q * 4];
    int wb = half * 28 + q * 4;
    tile[ci][wb + 0] = f2bf(v.x);
    tile[ci][wb + 1] = f2bf(v.y);
    tile[ci][wb + 2] = f2bf(v.z);
    tile[ci][wb + 3] = f2bf(v.w);
  }
  __syncthreads();
  if (t < 224) {
    int wo = t >> 2, chunk = t & 3;
    unsigned short* dst = xt + (size_t)b * 475136 + (size_t)(h + 1) * 8192 +
                          (size_t)(wo + 1) * 128 + chunk * 32;
    #pragma unroll
    for (int q = 0; q < 4; ++q) {
      ushort8v v;
      #pragma unroll
      for (int j = 0; j < 8; ++j) v[j] = tile[chunk * 32 + q * 8 + j][wo];
      *(ushort8v*)&dst[q * 8] = v;
    }
  }
}

// w[256][128][3][3] f32 -> wt[36 K-tiles][16KB staged-linear pre-swizzled]
// linear slot n (0..1023): p=n>>3, S=n&7, G=S^(p&7); co=(p<<1)|(G&1); g=G>>1
// slot holds bf16 of w[co][ci0+g*8 .. +8][tap]
__global__ void wtrans(const float* __restrict__ wsrc, unsigned short* __restrict__ wt) {
  int kt = blockIdx.x;    // 36
  int t = threadIdx.x;    // 256
  int tap = kt >> 2, ci0 = (kt & 3) * 32;
  int kh = tap >= 6 ? 2 : (tap >= 3 ? 1 : 0);
  int kw = tap - kh * 3;
  #pragma unroll
  for (int q = 0; q < 4; ++q) {
    int n = t + q * 256;
    int p = n >> 3, S = n & 7;
    int G = S ^ (p & 7);
    int g = G >> 1;
    int co = (p << 1) | (G & 1);
    const float* src = wsrc + (size_t)co * 1152 + (size_t)(ci0 + g * 8) * 9 + kh * 3 + kw;
    ushort8v v;
    #pragma unroll
    for (int j = 0; j < 8; ++j) v[j] = f2bf(src[j * 9]);
    *(ushort8v*)&wt[(size_t)kt * 8192 + n * 8] = v;
  }
}

// ---------------- main GEMM kernel ----------------
// LDS per buffer (32KB): A[256co][32k] sw. at +0, B[256px][32k] sw. at +16384.
// swizzle: byte(row,k) = (row>>1)*128 + ((((k>>3)<<1)|(row&1)) ^ ((row>>1)&7))*16 + (k&7)*2

__global__ __launch_bounds__(512, 2) void conv_gemm(
    const unsigned short* __restrict__ xt,
    const unsigned short* __restrict__ wt,
    const float* __restrict__ bias,
    float* __restrict__ out) {
  __shared__ __align__(16) char lds[98304];   // 3 x 32KB ring

  int bid = blockIdx.x;
  int sw = (bid & 7) * 28 + (bid >> 3);      // XCD swizzle, 224 = 8*28
  int bimg = sw / 14;
  int h0 = (sw - bimg * 14) * 4;             // 4 output rows (64px each) per tile

  int tid = threadIdx.x;
  int wv = tid >> 6, l = tid & 63;
  int wm = wv >> 2, wn = wv & 3;             // 2M x 4N waves, per-wave 128x64
  int lm = l & 15, lg = l >> 4;

  // fragment read offsets (conflict-free: 16 lanes -> 8 distinct 16B slots x2)
  int slotA = ((lg << 1) | (lm & 1)) ^ (lm >> 1);
  int aoff = wm * 8192 + (lm >> 1) * 128 + slotA * 16;
  int boff = 16384 + wn * 4096 + (lm >> 1) * 128 + slotA * 16;

  // A staging source (linear, pre-swizzled by wtrans)
  const char* aSrc = (const char*)wt + tid * 16;

  // B staging per-lane sources (pre-swizzled global address, rule 21)
  const unsigned short* bSrc0;
  const unsigned short* bSrc1;
  {
    int n = tid;
    int p = n >> 3, G = (n & 7) ^ (p & 7);
    int px = (p << 1) | (G & 1), g = G >> 1;
    bSrc0 = xt + ((size_t)((bimg * 58 + h0 + (px >> 6)) * 64 + (px & 63))) * 128 + g * 8;
    n = tid + 512;
    p = n >> 3; G = (n & 7) ^ (p & 7);
    px = (p << 1) | (G & 1); g = G >> 1;
    bSrc1 = xt + ((size_t)((bimg * 58 + h0 + (px >> 6)) * 64 + (px & 63))) * 128 + g * 8;
  }

  f32x4 acc[8][4];
  #pragma unroll
  for (int m = 0; m < 8; ++m)
    #pragma unroll
    for (int n = 0; n < 4; ++n)
      acc[m][n] = (f32x4){0.f, 0.f, 0.f, 0.f};

  auto stageA = [&](int kt2, int bufd) {
    const char* s = aSrc + kt2 * 16384;
    char* d = &lds[bufd * 32768 + wv * 1024];
    gll16(s, d);
    gll16(s + 8192, d + 8192);
  };
  auto stageB = [&](int kt2, int bufd) {
    int tap = kt2 >> 2;
    int kh = tap >= 6 ? 2 : (tap >= 3 ? 1 : 0);
    int kw = tap - kh * 3;
    int koff = (kh * 64 + kw) * 128 + (kt2 & 3) * 32;
    char* d = &lds[bufd * 32768 + 16384 + wv * 1024];
    gll16(bSrc0 + koff, d);
    gll16(bSrc1 + koff, d + 8192);
  };

  // prologue: stage kt0 -> buf0, kt1 -> buf1; wait oldest 4 (kt0) only
  stageA(0, 0); stageB(0, 0);
  stageA(1, 1); stageB(1, 1);
  asm volatile("s_waitcnt vmcnt(4)" ::: "memory");
  __builtin_amdgcn_sched_barrier(0);
  __builtin_amdgcn_s_barrier();
  __builtin_amdgcn_sched_barrier(0);

  int buf = 0;
  for (int kt = 0; kt < 36; ++kt) {
    const char* bA = &lds[buf * 32768];
    int bufd = buf >= 1 ? buf - 1 : 2;       // (buf+2)%3
    bf16x8 av[4], bv[4];
    // ---- phase 0: quadrants m=0..3, all n ----
    #pragma unroll
    for (int m = 0; m < 4; ++m) av[m] = *(const bf16x8*)(bA + aoff + m * 1024);
    #pragma unroll
    for (int n = 0; n < 4; ++n) bv[n] = *(const bf16x8*)(bA + boff + n * 1024);
    if (kt < 34) stageA(kt + 2, bufd);
    __builtin_amdgcn_s_barrier();
    __builtin_amdgcn_s_setprio(1);
    #pragma unroll
    for (int m = 0; m < 4; ++m)
      #pragma unroll
      for (int n = 0; n < 4; ++n)
        acc[m][n] = __builtin_amdgcn_mfma_f32_16x16x32_bf16(av[m], bv[n], acc[m][n], 0, 0, 0);
    __builtin_amdgcn_s_setprio(0);
    __builtin_amdgcn_s_barrier();
    // ---- phase 1: quadrants m=4..7, reuse bv ----
    #pragma unroll
    for (int m = 0; m < 4; ++m) av[m] = *(const bf16x8*)(bA + aoff + (m + 4) * 1024);
    if (kt < 34) stageB(kt + 2, bufd);
    __builtin_amdgcn_s_barrier();
    __builtin_amdgcn_s_setprio(1);
    #pragma unroll
    for (int m = 0; m < 4; ++m)
      #pragma unroll
      for (int n = 0; n < 4; ++n)
        acc[m + 4][n] = __builtin_amdgcn_mfma_f32_16x16x32_bf16(av[m], bv[n], acc[m + 4][n], 0, 0, 0);
    __builtin_amdgcn_s_setprio(0);
    // counted vmcnt: keep kt+2's 4 loads in flight, retire kt+1's (T4)
    if (kt < 34)      asm volatile("s_waitcnt vmcnt(4)" ::: "memory");
    else if (kt == 34) asm volatile("s_waitcnt vmcnt(0)" ::: "memory");
    __builtin_amdgcn_sched_barrier(0);
    __builtin_amdgcn_s_barrier();
    __builtin_amdgcn_sched_barrier(0);
    buf = buf == 2 ? 0 : buf + 1;
  }

  // epilogue: bias + masked store (w' < 56)
  #pragma unroll
  for (int m = 0; m < 8; ++m) {
    int co = wm * 128 + m * 16 + lg * 4;
    f32x4 bb = *(const f32x4*)&bias[co];
    size_t obase = ((size_t)bimg * 256 + co) * 3136;
    #pragma unroll
    for (int n = 0; n < 4; ++n) {
      int px = wn * 64 + n * 16 + lm;
      int w_ = px & 63;
      int h_ = h0 + (px >> 6);
      if (w_ < 56) {
        float* o = out + obase + (size_t)h_ * 56 + w_;
        #pragma unroll
        for (int r = 0; r < 4; ++r)
          o[(size_t)r * 3136] = acc[m][n][r] + bb[r];
      }
    }
  }
}

// ---------------- fallback (tiny ws) ----------------

__global__ void conv_naive(const float* __restrict__ x, const float* __restrict__ w,
                           const float* __restrict__ bias, float* __restrict__ out) {
  int idx = blockIdx.x * 256 + threadIdx.x;
  if (idx >= 16 * 256 * 56 * 56) return;
  int wo = idx % 56; int t = idx / 56;
  int ho = t % 56; t /= 56;
  int co = t % 256; int b = t / 256;
  float acc = bias[co];
  for (int ci = 0; ci < 128; ++ci) {
    const float* xp = x + ((size_t)(b * 128 + ci)) * 3136;
    const float* wp = w + ((size_t)(co * 128 + ci)) * 9;
    for (int kh = 0; kh < 3; ++kh) {
      int hi = ho + kh - 1;
      if (hi < 0 || hi >= 56) continue;
      for (int kw = 0; kw < 3; ++kw) {
        int wi = wo + kw - 1;
        if (wi < 0 || wi >= 56) continue;
        acc += xp[hi * 56 + wi] * wp[kh * 3 + kw];
      }
    }
  }
  out[idx] = acc;
}

extern "C" void kernel_launch(void* const* d_in, const int* in_sizes, int n_in,
                              void* d_out, int out_size, void* d_ws, size_t ws_size,
                              hipStream_t stream) {
  const float* x    = (const float*)d_in[0];
  const float* wgt  = (const float*)d_in[1];
  const float* bias = (const float*)d_in[2];
  float* out = (float*)d_out;

  if (ws_size < (size_t)WS_NEED) {
    conv_naive<<<(16 * 256 * 56 * 56 + 255) / 256, 256, 0, stream>>>(x, wgt, bias, out);
    return;
  }

  unsigned short* xt = (unsigned short*)d_ws;
  unsigned short* wt = (unsigned short*)((char*)d_ws + WT_OFFSET);

  fill_zero<<<1024, 256, 0, stream>>>((uint4*)d_ws, (int)(WT_OFFSET / 16));
  xtrans<<<896, 256, 0, stream>>>(x, xt);
  wtrans<<<36, 256, 0, stream>>>(wgt, wt);
  conv_gemm<<<224, 512, 0, stream>>>(xt, wt, bias, out);
}

// Round 3
// 57.783 us; speedup vs baseline: 1.6377x; 1.3227x over previous
//
#include <hip/hip_runtime.h>
#include <hip/hip_bf16.h>

// Conv2d: B=16, CIN=128, COUT=256, H=W=56, 3x3, stride1, pad1, fp32, + bias.
// Implicit GEMM, bf16 MFMA. M=256(co), N=16*56*64=57344(px, W padded 64), K=1152.
// R3: 256x256x64 tile, 8 waves, 2-buffer (128KB), ONE barrier per K-tile,
// stage-first ordering, R1-proven conflict-free XOR swizzle (slot = kg ^ (row&7)),
// setprio clusters (T5), XCD swizzle (T1, 224=8*28), fused prep pass.

#define XT_BYTES   15204352u   // 16*58*64*128*2
#define SLACK      8192u
#define WT_OFFSET  (XT_BYTES + SLACK)
#define WT_BYTES   589824u     // 18 * 32768
#define WS_NEED    (WT_OFFSET + WT_BYTES)

typedef __bf16 bf16x8 __attribute__((ext_vector_type(8)));
typedef float  f32x4  __attribute__((ext_vector_type(4)));
typedef unsigned short ushort8v __attribute__((ext_vector_type(8)));

__device__ __forceinline__ unsigned short f2bf(float f) {
  unsigned u = __builtin_bit_cast(unsigned, f);
  u += 0x7fffu + ((u >> 16) & 1u);
  return (unsigned short)(u >> 16);
}

__device__ __forceinline__ void gll16(const void* g, const void* l) {
  __builtin_amdgcn_global_load_lds(
      (const __attribute__((address_space(1))) unsigned int*)g,
      (__attribute__((address_space(3))) unsigned int*)l, 16, 0, 0);
}

// ---------------- fused prep kernel ----------------
// blocks 0..895: xtrans for (b,h) + zero pad-cols of that row
// blocks 896..927: zero rows 0 / 57 per image
// blocks 928..945: wtrans K-tile kt
__global__ void prep(const float* __restrict__ x, const float* __restrict__ wsrc,
                     unsigned short* __restrict__ xt, unsigned short* __restrict__ wt) {
  int blk = blockIdx.x;
  int t = threadIdx.x;   // 256
  if (blk < 896) {
    __shared__ unsigned short tile[128][58];
    int b = blk / 56, h = blk % 56;
    int ci = t >> 1, half = t & 1;
    const float* src = x + ((size_t)(b * 128 + ci)) * 3136 + h * 56 + half * 28;
    #pragma unroll
    for (int q = 0; q < 7; ++q) {
      float4 v = *(const float4*)&src[q * 4];
      int wb = half * 28 + q * 4;
      tile[ci][wb + 0] = f2bf(v.x);
      tile[ci][wb + 1] = f2bf(v.y);
      tile[ci][wb + 2] = f2bf(v.z);
      tile[ci][wb + 3] = f2bf(v.w);
    }
    unsigned short* row = xt + (size_t)b * 475136 + (size_t)(h + 1) * 8192;
    if (t < 128) {  // zero pad cols 0, 57..63 of this padded row
      int slot = t >> 4;
      int px = slot ? 56 + slot : 0;
      uint4 z; z.x = z.y = z.z = z.w = 0u;
      *(uint4*)(row + px * 128 + (t & 15) * 8) = z;
    }
    __syncthreads();
    if (t < 224) {
      int wo = t >> 2, chunk = t & 3;
      unsigned short* dst = row + (size_t)(wo + 1) * 128 + chunk * 32;
      #pragma unroll
      for (int q = 0; q < 4; ++q) {
        ushort8v v;
        #pragma unroll
        for (int j = 0; j < 8; ++j) v[j] = tile[chunk * 32 + q * 8 + j][wo];
        *(ushort8v*)&dst[q * 8] = v;
      }
    }
  } else if (blk < 928) {
    int idx = blk - 896;
    int b = idx >> 1, zr = (idx & 1) ? 57 : 0;
    uint4* dst = (uint4*)(xt + (size_t)b * 475136 + (size_t)zr * 8192);
    uint4 z; z.x = z.y = z.z = z.w = 0u;
    #pragma unroll
    for (int q = 0; q < 4; ++q) dst[t + q * 256] = z;
  } else {
    int kt = blk - 928;          // 0..17
    int tap = kt >> 1;
    int ci0 = (kt & 1) * 64;
    #pragma unroll
    for (int q = 0; q < 8; ++q) {
      int n = t + q * 256;       // 0..2047
      int co = n >> 3;
      int kg = (n & 7) ^ (co & 7);
      const float* src = wsrc + (size_t)co * 1152 + (size_t)(ci0 + kg * 8) * 9 + tap;
      ushort8v v;
      #pragma unroll
      for (int j = 0; j < 8; ++j) v[j] = f2bf(src[j * 9]);
      *(ushort8v*)&wt[(size_t)kt * 16384 + n * 8] = v;
    }
  }
}

// ---------------- main GEMM kernel ----------------
// LDS buffer (64KB): A [256co][64k] at +0, B [256px][64k] at +32768.
// swizzle: byte(r,k) = r*128 + ((k>>3) ^ (r&7))*16 + (k&7)*2   (conflict-free)

__global__ __launch_bounds__(512, 2) void conv_gemm(
    const unsigned short* __restrict__ xt,
    const char* __restrict__ wt,
    const float* __restrict__ bias,
    float* __restrict__ out) {
  __shared__ __align__(16) char lds[131072];   // 2 x 64KB

  int bid = blockIdx.x;
  int sw = (bid & 7) * 28 + (bid >> 3);        // XCD swizzle, 224 = 8*28
  int bimg = sw / 14;
  int h0 = (sw - bimg * 14) * 4;               // 4 output rows per tile

  int tid = threadIdx.x;
  int wv = tid >> 6, l = tid & 63;
  int wm = wv >> 2, wn = wv & 3;               // 2M x 4N waves, 128x64 each
  int lm = l & 15, lg = l >> 4, x7 = lm & 7;

  int aoff0 = wm * 16384 + lm * 128 + ((lg ^ x7) << 4);
  int boff0 = 32768 + wn * 8192 + lm * 128 + ((lg ^ x7) << 4);

  // staging sources (LDS dest linear; inverse swizzle folded into source)
  const char* aB = wt + wv * 4096 + l * 16;
  const unsigned short* bB[4];
  #pragma unroll
  for (int q = 0; q < 4; ++q) {
    int n = wv * 256 + q * 64 + l;
    int px = n >> 3;
    int kg = (n & 7) ^ (px & 7);
    bB[q] = xt + ((size_t)((bimg * 58 + h0 + (px >> 6)) * 64 + (px & 63))) * 128 + kg * 8;
  }

  f32x4 acc[8][4];
  #pragma unroll
  for (int m = 0; m < 8; ++m)
    #pragma unroll
    for (int n = 0; n < 4; ++n)
      acc[m][n] = (f32x4){0.f, 0.f, 0.f, 0.f};

  auto stage = [&](int kt, int buf) {
    int tap = kt >> 1;
    int kh = tap >= 6 ? 2 : (tap >= 3 ? 1 : 0);
    int kw = tap - kh * 3;
    int koff = (kh * 64 + kw) * 128 + (kt & 1) * 64;   // ushort units
    char* dA = &lds[buf * 65536 + wv * 4096];
    char* dB = &lds[buf * 65536 + 32768 + wv * 4096];
    const char* sA = aB + kt * 32768;
    #pragma unroll
    for (int q = 0; q < 4; ++q) {
      gll16(sA + q * 1024, dA + q * 1024);
      gll16(bB[q] + koff, dB + q * 1024);
    }
  };

  stage(0, 0);
  __syncthreads();

  for (int kt = 0; kt < 18; ++kt) {
    const char* base = &lds[(kt & 1) * 65536];
    if (kt < 17) stage(kt + 1, (kt + 1) & 1);   // issue-early: latency under compute
    bf16x8 a0[8], b0[4];
    #pragma unroll
    for (int m = 0; m < 8; ++m) a0[m] = *(const bf16x8*)(base + aoff0 + m * 2048);
    #pragma unroll
    for (int n = 0; n < 4; ++n) b0[n] = *(const bf16x8*)(base + boff0 + n * 2048);
    __builtin_amdgcn_s_setprio(1);
    #pragma unroll
    for (int m = 0; m < 8; ++m)
      #pragma unroll
      for (int n = 0; n < 4; ++n)
        acc[m][n] = __builtin_amdgcn_mfma_f32_16x16x32_bf16(a0[m], b0[n], acc[m][n], 0, 0, 0);
    __builtin_amdgcn_s_setprio(0);
    bf16x8 a1[8], b1[4];
    #pragma unroll
    for (int m = 0; m < 8; ++m) a1[m] = *(const bf16x8*)(base + ((aoff0 ^ 64) + m * 2048));
    #pragma unroll
    for (int n = 0; n < 4; ++n) b1[n] = *(const bf16x8*)(base + ((boff0 ^ 64) + n * 2048));
    __builtin_amdgcn_s_setprio(1);
    #pragma unroll
    for (int m = 0; m < 8; ++m)
      #pragma unroll
      for (int n = 0; n < 4; ++n)
        acc[m][n] = __builtin_amdgcn_mfma_f32_16x16x32_bf16(a1[m], b1[n], acc[m][n], 0, 0, 0);
    __builtin_amdgcn_s_setprio(0);
    if (kt < 17) __syncthreads();   // single sync point per K-tile
  }

  // epilogue: bias + masked store (w' < 56)
  #pragma unroll
  for (int m = 0; m < 8; ++m) {
    int co = wm * 128 + m * 16 + lg * 4;
    f32x4 bb = *(const f32x4*)&bias[co];
    size_t obase = ((size_t)bimg * 256 + co) * 3136;
    #pragma unroll
    for (int n = 0; n < 4; ++n) {
      int px = wn * 64 + n * 16 + lm;
      int w_ = px & 63;
      int h_ = h0 + (px >> 6);
      if (w_ < 56) {
        float* o = out + obase + (size_t)h_ * 56 + w_;
        #pragma unroll
        for (int r = 0; r < 4; ++r)
          o[(size_t)r * 3136] = acc[m][n][r] + bb[r];
      }
    }
  }
}

// ---------------- fallback (tiny ws) ----------------

__global__ void conv_naive(const float* __restrict__ x, const float* __restrict__ w,
                           const float* __restrict__ bias, float* __restrict__ out) {
  int idx = blockIdx.x * 256 + threadIdx.x;
  if (idx >= 16 * 256 * 56 * 56) return;
  int wo = idx % 56; int t = idx / 56;
  int ho = t % 56; t /= 56;
  int co = t % 256; int b = t / 256;
  float acc = bias[co];
  for (int ci = 0; ci < 128; ++ci) {
    const float* xp = x + ((size_t)(b * 128 + ci)) * 3136;
    const float* wp = w + ((size_t)(co * 128 + ci)) * 9;
    for (int kh = 0; kh < 3; ++kh) {
      int hi = ho + kh - 1;
      if (hi < 0 || hi >= 56) continue;
      for (int kw = 0; kw < 3; ++kw) {
        int wi = wo + kw - 1;
        if (wi < 0 || wi >= 56) continue;
        acc += xp[hi * 56 + wi] * wp[kh * 3 + kw];
      }
    }
  }
  out[idx] = acc;
}

extern "C" void kernel_launch(void* const* d_in, const int* in_sizes, int n_in,
                              void* d_out, int out_size, void* d_ws, size_t ws_size,
                              hipStream_t stream) {
  const float* x    = (const float*)d_in[0];
  const float* wgt  = (const float*)d_in[1];
  const float* bias = (const float*)d_in[2];
  float* out = (float*)d_out;

  if (ws_size < (size_t)WS_NEED) {
    conv_naive<<<(16 * 256 * 56 * 56 + 255) / 256, 256, 0, stream>>>(x, wgt, bias, out);
    return;
  }

  unsigned short* xt = (unsigned short*)d_ws;
  unsigned short* wt = (unsigned short*)((char*)d_ws + WT_OFFSET);

  prep<<<946, 256, 0, stream>>>(x, wgt, xt, wt);
  conv_gemm<<<224, 512, 0, stream>>>(xt, (const char*)wt, bias, out);
}